// Round 14
// baseline (537.226 us; speedup 1.0000x reference)
//
#include <hip/hip_runtime.h>
#include <math.h>
#include <stdint.h>

typedef _Float16 f16;
typedef _Float16 f16x8 __attribute__((ext_vector_type(8)));
typedef float f32x4 __attribute__((ext_vector_type(4)));
typedef unsigned short u16;
typedef u16 u16x8 __attribute__((ext_vector_type(8)));

#define HID 256
#define NS1C 100              // layer-1 conv K-steps: 25 taps x 4 channel-groups
#define NS2 8                 // 256/32
#define NPX 65536
#define BPXG 256              // pixels per block (one full image row)
#define NBG (NPX/BPXG)        // 256 blocks -> 1 round at 1 block/CU
#define SPAD 260
#define NSP (SPAD*SPAD)

// ws layout (bytes) — same as r13 (~106 MB, fits; proven r9)
#define OFF_W1C 0
#define SZ_W1C  ((size_t)NS1C*32768)
#define OFF_W2  SZ_W1C
#define SZ_W2   ((size_t)NS2*32768)
#define OFF_W3  (OFF_W2+SZ_W2)
#define OFF_XH  ((size_t)4194304)
#define SZ_XP   ((size_t)NSP*128*2)
#define OFF_XL  (OFF_XH + SZ_XP)
#define OFF_HH  (OFF_XL + SZ_XP)
#define SZ_HP   ((size_t)NPX*HID*2)
#define OFF_HL  (OFF_HH + SZ_HP)

__device__ inline void split2(float v, u16& h, u16& l){
  f16 hv = (f16)v;
  f16 lv = (f16)(v - (float)hv);
  h = __builtin_bit_cast(u16, hv);
  l = __builtin_bit_cast(u16, lv);
}

// prep_w: W (fp32 [K][256]) -> fp16 hi/lo MFMA-fragment units (proven layout)
__global__ void prep_w(const float* __restrict__ W, int Kact, int nStages,
                       u16* __restrict__ outp){
  int t = blockIdx.x*256 + threadIdx.x;
  if (t >= nStages*1024) return;
  int s = t >> 10, r = t & 1023;
  int w = r >> 8, nf = (r >> 6) & 3, l = r & 63;
  int col = w*64 + nf*16 + (l & 15);
  int kb  = s*32 + (l >> 4)*8;
  u16x8 hv, lv;
  #pragma unroll
  for (int j = 0; j < 8; ++j){
    int k = kb + j;
    float v = (k < Kact) ? W[(size_t)k*HID + col] : 0.f;
    u16 h, lo; split2(v, h, lo);
    hv[j] = h; lv[j] = lo;
  }
  size_t U0 = ((((size_t)s*4 + w)*4 + nf)*2 + 0)*64 + l;
  *(u16x8*)(outp + U0*8)      = hv;
  *(u16x8*)(outp + (U0+64)*8) = lv;
}

// prep_w1c: W1 rows 0..3199 tap-major (step s: tap=s>>2, cg=s&3; k=c*25+tap)
__global__ void prep_w1c(const float* __restrict__ W1, u16* __restrict__ outp){
  int t = blockIdx.x*256 + threadIdx.x;
  if (t >= NS1C*1024) return;
  int s = t >> 10, r = t & 1023;
  int w = r >> 8, nf = (r >> 6) & 3, l = r & 63;
  int col = w*64 + nf*16 + (l & 15);
  int tap = s >> 2, cg = s & 3;
  int cb  = cg*32 + (l >> 4)*8;
  u16x8 hv, lv;
  #pragma unroll
  for (int j = 0; j < 8; ++j){
    int c = cb + j;
    float v = W1[(size_t)(c*25 + tap)*HID + col];
    u16 h, lo; split2(v, h, lo);
    hv[j] = h; lv[j] = lo;
  }
  size_t U0 = ((((size_t)s*4 + w)*4 + nf)*2 + 0)*64 + l;
  *(u16x8*)(outp + U0*8)      = hv;
  *(u16x8*)(outp + (U0+64)*8) = lv;
}

// prep_x: zero-padded channel-interleaved hi/lo planes (r11-proven)
__global__ __launch_bounds__(256)
void prep_x(const float* __restrict__ xi, u16* __restrict__ Xh, u16* __restrict__ Xl){
  int sp = blockIdx.x*256 + threadIdx.x;
  if (sp >= NSP) return;
  int py = sp / SPAD;
  int px = sp - py*SPAD;
  bool inb = (py >= 2) & (py < 258) & (px >= 2) & (px < 258);
  const float* xin = xi + ((size_t)(py-2)<<8) + (px-2);
  #pragma unroll 4
  for (int cg = 0; cg < 16; ++cg){
    u16x8 hv, lv;
    #pragma unroll
    for (int j = 0; j < 8; ++j){
      float v = inb ? xin[((size_t)(cg*8 + j))<<16] : 0.f;
      u16 h, l; split2(v, h, l); hv[j] = h; lv[j] = l;
    }
    *(u16x8*)(Xh + (size_t)sp*128 + cg*8) = hv;
    *(u16x8*)(Xl + (size_t)sp*128 + cg*8) = lv;
  }
}

// ---------------------------------------------------------------------------
// 256px x 256col GEMM, 512 thr = 8 waves (wave = 128px x 64col, 96 MFMA/step),
// 2-buffer LDS, counted vmcnt(8) + raw barriers (r13-proven), now with the
// m201-style 4-PHASE compute split: phase p = {ds_read A-frags mf=2p,2p+1
// (phase 0 also all B-frags) -> s_barrier -> MFMA cluster}. Phase p+1's LDS
// reads hide under phase p's MFMA drain; barriers pin the rhythm.
// Staging still only after the end-of-step all-reads-retired barrier.
// MODE 0: A = conv taps of Xh/Xl, nt=100, epilogue exact-f32 coords.
// MODE 1: A = Hh/Hl, nt=8. MODE 2: + fused layer-4 tail.
// ---------------------------------------------------------------------------
template<int MODE>
__global__ __launch_bounds__(512, 2)
void gemm(const u16* __restrict__ Ah, const u16* __restrict__ Al,
          const u16* __restrict__ Wp, const float* __restrict__ W1,
          const float* __restrict__ bias, u16* __restrict__ Hh, u16* __restrict__ Hl,
          const float* __restrict__ W4, const float* __restrict__ b4,
          float* __restrict__ out, int nt)
{
  __shared__ __align__(16) u16 Ab[2][16384];   // 32 KB/buf: [mfb(16)][split(2)][unit(64)][8]
  __shared__ __align__(16) u16 Bb[2][16384];   // 32 KB/buf: [g(16)][split(2)][unit(64)][8]

  const int tid  = threadIdx.x;
  const int lane = tid & 63;
  const int wv   = tid >> 6;            // 0..7
  const int wm   = wv >> 2, wn = wv & 3;

  int bid = blockIdx.x;
  bid = (bid & 7)*(NBG/8) + (bid >> 3);   // XCD-chunked swizzle (256%8==0)
  const int pxb = bid * BPXG;             // one full image row
  const int y   = bid;                    // row index

  f32x4 acc[8][4];
  #pragma unroll
  for (int a=0;a<8;a++)
    #pragma unroll
    for (int bq=0;bq<4;bq++) acc[a][bq] = f32x4{0.f,0.f,0.f,0.f};

  // A-stage: wave wv stages mfb = wv*2+u (u=0,1), hi+lo -> 4 DMA/wave.
#define A_STAGE(S, BUF) do { \
    _Pragma("unroll") \
    for (int u=0;u<2;++u){ \
      const int mfb = wv*2 + u; \
      size_t off; \
      if (MODE == 0){ \
        const int tap = (S) >> 2, cg = (S) & 3; \
        const int dy = tap/5, dx = tap - 5*dy; \
        const int sp = (y + dy)*SPAD + dx + mfb*16 + (lane & 15); \
        off = (size_t)sp*128 + cg*32 + (lane >> 4)*8; \
      } else { \
        const int px = pxb + mfb*16 + (lane & 15); \
        off = (size_t)px*HID + (S)*32 + (lane >> 4)*8; \
      } \
      __builtin_amdgcn_global_load_lds( \
        (const __attribute__((address_space(1))) uint32_t*)(Ah + off), \
        (__attribute__((address_space(3))) uint32_t*)((char*)&Ab[BUF][0] + (mfb*2+0)*1024), \
        16, 0, 0); \
      __builtin_amdgcn_global_load_lds( \
        (const __attribute__((address_space(1))) uint32_t*)(Al + off), \
        (__attribute__((address_space(3))) uint32_t*)((char*)&Ab[BUF][0] + (mfb*2+1)*1024), \
        16, 0, 0); \
    } \
  } while(0)

  // B-stage: linear 32 KB slab copy; wave wv covers [wv*4096, +4096) -> 4 DMA.
#define B_STAGE(S, BUF) do { \
    const char* _src = (const char*)Wp + (size_t)(S)*32768 + wv*4096 + lane*16; \
    char* _dst = (char*)&Bb[BUF][0] + wv*4096; \
    _Pragma("unroll") \
    for (int i=0;i<4;++i) \
      __builtin_amdgcn_global_load_lds( \
        (const __attribute__((address_space(1))) uint32_t*)(_src + i*1024), \
        (__attribute__((address_space(3))) uint32_t*)(_dst + i*1024), 16, 0, 0); \
  } while(0)

  // prologue: 2 stages in flight
  A_STAGE(0, 0); B_STAGE(0, 0);
  A_STAGE(1, 1); B_STAGE(1, 1);

  for (int t = 0; t < nt; ++t){
    // counted wait: only stage(t+1)'s 8 vmem instr may remain outstanding
    if (t+1 < nt) { asm volatile("s_waitcnt vmcnt(8)" ::: "memory"); }
    else          { asm volatile("s_waitcnt vmcnt(0)" ::: "memory"); }
    __builtin_amdgcn_s_barrier();          // buf(t&1) fully staged (all waves)
    __builtin_amdgcn_sched_barrier(0);
    const int cur = t & 1;

    // phase 0 reads: all 8 B-frags + A-frags for mf 0,1
    f16x8 bh[4], bl[4];
    #pragma unroll
    for (int nf=0;nf<4;++nf){
      bh[nf] = *(const f16x8*)(&Bb[cur][((size_t)((wn*4+nf)*2+0)*64 + lane)*8]);
      bl[nf] = *(const f16x8*)(&Bb[cur][((size_t)((wn*4+nf)*2+1)*64 + lane)*8]);
    }
    #pragma unroll
    for (int p=0;p<4;++p){
      f16x8 pah[2], pal[2];
      #pragma unroll
      for (int u=0;u<2;++u){
        const int mfb = wm*8 + p*2 + u;
        pah[u] = *(const f16x8*)(&Ab[cur][((size_t)(mfb*2+0)*64 + lane)*8]);
        pal[u] = *(const f16x8*)(&Ab[cur][((size_t)(mfb*2+1)*64 + lane)*8]);
      }
      __builtin_amdgcn_s_barrier();            // phase rhythm: reads | MFMA drain
      __builtin_amdgcn_sched_barrier(0);
      __builtin_amdgcn_s_setprio(1);
      #pragma unroll
      for (int u=0;u<2;++u){
        const int mf = p*2 + u;
        #pragma unroll
        for (int nf=0;nf<4;++nf){
          acc[mf][nf] = __builtin_amdgcn_mfma_f32_16x16x32_f16(pah[u], bh[nf], acc[mf][nf], 0,0,0);
          acc[mf][nf] = __builtin_amdgcn_mfma_f32_16x16x32_f16(pal[u], bh[nf], acc[mf][nf], 0,0,0);
          acc[mf][nf] = __builtin_amdgcn_mfma_f32_16x16x32_f16(pah[u], bl[nf], acc[mf][nf], 0,0,0);
        }
      }
      __builtin_amdgcn_s_setprio(0);
    }
    asm volatile("s_waitcnt lgkmcnt(0)" ::: "memory");  // all my ds_reads retired
    __builtin_amdgcn_sched_barrier(0);
    __builtin_amdgcn_s_barrier();          // all waves done reading buf(cur)
    if (t+2 < nt){
      A_STAGE(t+2, cur);                   // refill the buffer just consumed
      B_STAGE(t+2, cur);
    }
  }

  float bcol[4];
  #pragma unroll
  for (int nf=0;nf<4;++nf) bcol[nf] = bias[wn*64 + nf*16 + (lane&15)];

  if (MODE == 0){
    float wyv[4], wxv[4];
    #pragma unroll
    for (int nf=0;nf<4;++nf){
      int col = wn*64 + nf*16 + (lane&15);
      wyv[nf] = W1[(size_t)3200*HID + col];
      wxv[nf] = W1[(size_t)3201*HID + col];
    }
    const float gy = -1.f + (2.f/255.f)*(float)y;
    #pragma unroll
    for (int mf=0;mf<8;++mf)
      #pragma unroll
      for (int nf=0;nf<4;++nf)
        #pragma unroll
        for (int j=0;j<4;++j){
          int row = wm*128 + mf*16 + (lane>>4)*4 + j;          // 0..255 = x coord
          float gx = -1.f + (2.f/255.f)*(float)row;
          float z = acc[mf][nf][j] + bcol[nf] + gy*wyv[nf] + gx*wxv[nf];
          float h = sinf(30.f*z);
          u16 hh,ll; split2(h,hh,ll);
          int col = wn*64 + nf*16 + (lane&15);
          size_t o = (size_t)(pxb+row)*HID + col;
          Hh[o] = hh; Hl[o] = ll;
        }
  } else if (MODE == 1){
    #pragma unroll
    for (int mf=0;mf<8;++mf)
      #pragma unroll
      for (int nf=0;nf<4;++nf)
        #pragma unroll
        for (int j=0;j<4;++j){
          float z = acc[mf][nf][j] + bcol[nf];
          float h = sinf(30.f*z);
          u16 hh,ll; split2(h,hh,ll);
          int row = wm*128 + mf*16 + (lane>>4)*4 + j;
          int col = wn*64 + nf*16 + (lane&15);
          size_t o = (size_t)(pxb+row)*HID + col;
          Hh[o] = hh; Hl[o] = ll;
        }
  } else {
    float (*red)[BPXG][3] = (float(*)[BPXG][3])(void*)&Ab[0][0];  // 24 KB overlay, bufs dead
    float w4v[4][3];
    #pragma unroll
    for (int nf=0;nf<4;++nf){
      int col = wn*64 + nf*16 + (lane&15);
      w4v[nf][0]=W4[col*3+0]; w4v[nf][1]=W4[col*3+1]; w4v[nf][2]=W4[col*3+2];
    }
    #pragma unroll
    for (int mf=0;mf<8;++mf)
      #pragma unroll
      for (int j=0;j<4;++j){
        float s0=0.f,s1=0.f,s2=0.f;
        #pragma unroll
        for (int nf=0;nf<4;++nf){
          float h = sinf(30.f*(acc[mf][nf][j] + bcol[nf]));
          s0 += h*w4v[nf][0]; s1 += h*w4v[nf][1]; s2 += h*w4v[nf][2];
        }
        #pragma unroll
        for (int m=1;m<16;m<<=1){
          s0 += __shfl_xor(s0, m);
          s1 += __shfl_xor(s1, m);
          s2 += __shfl_xor(s2, m);
        }
        if ((lane & 15) == 0){
          int row = wm*128 + mf*16 + (lane>>4)*4 + j;
          red[wn + wm*4][row][0]=s0; red[wn + wm*4][row][1]=s1; red[wn + wm*4][row][2]=s2;
        }
      }
    __syncthreads();
    for (int o = tid; o < BPXG*3; o += 512){
      int px = o & 255, c = o >> 8;
      int wb = (px >> 7)*4;    // waves with wm = px>>7 hold this row
      float v = red[wb+0][px][c]+red[wb+1][px][c]+red[wb+2][px][c]+red[wb+3][px][c] + b4[c];
      out[(size_t)c*NPX + pxb + px] = v;
    }
  }
#undef A_STAGE
#undef B_STAGE
}

// ---------------------------------------------------------------------------
extern "C" void kernel_launch(void* const* d_in, const int* in_sizes, int n_in,
                              void* d_out, int out_size, void* d_ws, size_t ws_size,
                              hipStream_t stream) {
  const float* xi = (const float*)d_in[0];
  const float* W1 = (const float*)d_in[1];
  const float* b1 = (const float*)d_in[2];
  const float* W2 = (const float*)d_in[3];
  const float* b2 = (const float*)d_in[4];
  const float* W3 = (const float*)d_in[5];
  const float* b3 = (const float*)d_in[6];
  const float* W4 = (const float*)d_in[7];
  const float* b4 = (const float*)d_in[8];
  float* out = (float*)d_out;

  char* ws = (char*)d_ws;
  u16* W1c = (u16*)(ws + OFF_W1C);
  u16* W2p = (u16*)(ws + OFF_W2);
  u16* W3p = (u16*)(ws + OFF_W3);
  u16* Xh  = (u16*)(ws + OFF_XH);
  u16* Xl  = (u16*)(ws + OFF_XL);
  u16* Hh  = (u16*)(ws + OFF_HH);
  u16* Hl  = (u16*)(ws + OFF_HL);

  prep_w1c<<<NS1C*4, 256, 0, stream>>>(W1, W1c);
  prep_w<<<NS2*4, 256, 0, stream>>>(W2, HID, NS2, W2p);
  prep_w<<<NS2*4, 256, 0, stream>>>(W3, HID, NS2, W3p);
  prep_x<<<(NSP + 255)/256, 256, 0, stream>>>(xi, Xh, Xl);

  dim3 grid(NBG), block(512);
  gemm<0><<<grid, block, 0, stream>>>(Xh, Xl, W1c, W1, b1, Hh, Hl,
                                      nullptr, nullptr, nullptr, NS1C);
  gemm<1><<<grid, block, 0, stream>>>(Hh, Hl, W2p, nullptr, b2, Hh, Hl,
                                      nullptr, nullptr, nullptr, NS2);
  gemm<2><<<grid, block, 0, stream>>>(Hh, Hl, W3p, nullptr, b3, nullptr, nullptr,
                                      W4, b4, out, NS2);
}

// Round 15
// 506.941 us; speedup vs baseline: 1.0597x; 1.0597x over previous
//
#include <hip/hip_runtime.h>
#include <math.h>
#include <stdint.h>

typedef _Float16 f16;
typedef _Float16 f16x8 __attribute__((ext_vector_type(8)));
typedef float f32x4 __attribute__((ext_vector_type(4)));
typedef unsigned short u16;
typedef u16 u16x8 __attribute__((ext_vector_type(8)));

#define HID 256
#define NS1C 100              // layer-1 conv K-steps: 25 taps x 4 channel-groups
#define NS2 8                 // 256/32
#define NPX 65536
#define BPXG 256              // pixels per block (one full image row)
#define NBG (NPX/BPXG)        // 256 blocks -> 1 round at 1 block/CU
#define SPAD 260
#define NSP (SPAD*SPAD)

// ws layout (bytes) — same as r13 (~106 MB, fits; proven r9)
#define OFF_W1C 0
#define SZ_W1C  ((size_t)NS1C*32768)
#define OFF_W2  SZ_W1C
#define SZ_W2   ((size_t)NS2*32768)
#define OFF_W3  (OFF_W2+SZ_W2)
#define OFF_XH  ((size_t)4194304)
#define SZ_XP   ((size_t)NSP*128*2)
#define OFF_XL  (OFF_XH + SZ_XP)
#define OFF_HH  (OFF_XL + SZ_XP)
#define SZ_HP   ((size_t)NPX*HID*2)
#define OFF_HL  (OFF_HH + SZ_HP)

__device__ inline void split2(float v, u16& h, u16& l){
  f16 hv = (f16)v;
  f16 lv = (f16)(v - (float)hv);
  h = __builtin_bit_cast(u16, hv);
  l = __builtin_bit_cast(u16, lv);
}

// prep_w: W (fp32 [K][256]) -> fp16 hi/lo MFMA-fragment units (proven layout)
__global__ void prep_w(const float* __restrict__ W, int Kact, int nStages,
                       u16* __restrict__ outp){
  int t = blockIdx.x*256 + threadIdx.x;
  if (t >= nStages*1024) return;
  int s = t >> 10, r = t & 1023;
  int w = r >> 8, nf = (r >> 6) & 3, l = r & 63;
  int col = w*64 + nf*16 + (l & 15);
  int kb  = s*32 + (l >> 4)*8;
  u16x8 hv, lv;
  #pragma unroll
  for (int j = 0; j < 8; ++j){
    int k = kb + j;
    float v = (k < Kact) ? W[(size_t)k*HID + col] : 0.f;
    u16 h, lo; split2(v, h, lo);
    hv[j] = h; lv[j] = lo;
  }
  size_t U0 = ((((size_t)s*4 + w)*4 + nf)*2 + 0)*64 + l;
  *(u16x8*)(outp + U0*8)      = hv;
  *(u16x8*)(outp + (U0+64)*8) = lv;
}

// prep_w1c: W1 rows 0..3199 tap-major (step s: tap=s>>2, cg=s&3; k=c*25+tap)
__global__ void prep_w1c(const float* __restrict__ W1, u16* __restrict__ outp){
  int t = blockIdx.x*256 + threadIdx.x;
  if (t >= NS1C*1024) return;
  int s = t >> 10, r = t & 1023;
  int w = r >> 8, nf = (r >> 6) & 3, l = r & 63;
  int col = w*64 + nf*16 + (l & 15);
  int tap = s >> 2, cg = s & 3;
  int cb  = cg*32 + (l >> 4)*8;
  u16x8 hv, lv;
  #pragma unroll
  for (int j = 0; j < 8; ++j){
    int c = cb + j;
    float v = W1[(size_t)(c*25 + tap)*HID + col];
    u16 h, lo; split2(v, h, lo);
    hv[j] = h; lv[j] = lo;
  }
  size_t U0 = ((((size_t)s*4 + w)*4 + nf)*2 + 0)*64 + l;
  *(u16x8*)(outp + U0*8)      = hv;
  *(u16x8*)(outp + (U0+64)*8) = lv;
}

// prep_x: zero-padded channel-interleaved hi/lo planes (r11-proven)
__global__ __launch_bounds__(256)
void prep_x(const float* __restrict__ xi, u16* __restrict__ Xh, u16* __restrict__ Xl){
  int sp = blockIdx.x*256 + threadIdx.x;
  if (sp >= NSP) return;
  int py = sp / SPAD;
  int px = sp - py*SPAD;
  bool inb = (py >= 2) & (py < 258) & (px >= 2) & (px < 258);
  const float* xin = xi + ((size_t)(py-2)<<8) + (px-2);
  #pragma unroll 4
  for (int cg = 0; cg < 16; ++cg){
    u16x8 hv, lv;
    #pragma unroll
    for (int j = 0; j < 8; ++j){
      float v = inb ? xin[((size_t)(cg*8 + j))<<16] : 0.f;
      u16 h, l; split2(v, h, l); hv[j] = h; lv[j] = l;
    }
    *(u16x8*)(Xh + (size_t)sp*128 + cg*8) = hv;
    *(u16x8*)(Xl + (size_t)sp*128 + cg*8) = lv;
  }
}

// ---------------------------------------------------------------------------
// 256px x 256col GEMM, 512 thr = 8 waves (wave = 128px x 64col, 96 MFMA/step).
// ONE barrier per step (r13's 2nd barrier proven redundant: a wave reaching
// the top barrier has consumed all its prior-step ds_reads via lgkmcnt, so
// buf cur^1 is free right after the barrier). Staging for t+1 is issued at
// the TOP of step t -> full step of latency cover; vmcnt(0) at top is free.
// LDS: single 128 KB pool Sb: A bufs at byte {0,32768}, B at {65536,98304}.
// Epilogue (MODE 0/1): LDS-transpose coalesced H stores (16 B/lane).
// MODE 0: A = conv taps of Xh/Xl, nt=100, exact-f32 coords in epilogue.
// MODE 1: A = Hh/Hl, nt=8. MODE 2: + fused layer-4 tail.
// ---------------------------------------------------------------------------
template<int MODE>
__global__ __launch_bounds__(512, 2)
void gemm(const u16* __restrict__ Ah, const u16* __restrict__ Al,
          const u16* __restrict__ Wp, const float* __restrict__ W1,
          const float* __restrict__ bias, u16* __restrict__ Hh, u16* __restrict__ Hl,
          const float* __restrict__ W4, const float* __restrict__ b4,
          float* __restrict__ out, int nt)
{
  __shared__ __align__(16) u16 Sb[65536];   // 128 KB pool

  const int tid  = threadIdx.x;
  const int lane = tid & 63;
  const int wv   = tid >> 6;            // 0..7
  const int wm   = wv >> 2, wn = wv & 3;

  int bid = blockIdx.x;
  bid = (bid & 7)*(NBG/8) + (bid >> 3);   // XCD-chunked swizzle (256%8==0)
  const int pxb = bid * BPXG;             // one full image row
  const int y   = bid;                    // row index

  f32x4 acc[8][4];
  #pragma unroll
  for (int a=0;a<8;a++)
    #pragma unroll
    for (int bq=0;bq<4;bq++) acc[a][bq] = f32x4{0.f,0.f,0.f,0.f};

  // A-stage: wave wv stages mfb = wv*2+u (u=0,1), hi+lo -> 4 DMA/thread.
#define A_STAGE(S, BUF) do { \
    _Pragma("unroll") \
    for (int u=0;u<2;++u){ \
      const int mfb = wv*2 + u; \
      size_t off; \
      if (MODE == 0){ \
        const int tap = (S) >> 2, cg = (S) & 3; \
        const int dy = tap/5, dx = tap - 5*dy; \
        const int sp = (y + dy)*SPAD + dx + mfb*16 + (lane & 15); \
        off = (size_t)sp*128 + cg*32 + (lane >> 4)*8; \
      } else { \
        const int px = pxb + mfb*16 + (lane & 15); \
        off = (size_t)px*HID + (S)*32 + (lane >> 4)*8; \
      } \
      __builtin_amdgcn_global_load_lds( \
        (const __attribute__((address_space(1))) uint32_t*)(Ah + off), \
        (__attribute__((address_space(3))) uint32_t*)((char*)Sb + (size_t)(BUF)*32768 + (mfb*2+0)*1024), \
        16, 0, 0); \
      __builtin_amdgcn_global_load_lds( \
        (const __attribute__((address_space(1))) uint32_t*)(Al + off), \
        (__attribute__((address_space(3))) uint32_t*)((char*)Sb + (size_t)(BUF)*32768 + (mfb*2+1)*1024), \
        16, 0, 0); \
    } \
  } while(0)

  // B-stage: linear 32 KB slab copy; wave wv covers [wv*4096, +4096) -> 4 DMA/thread.
#define B_STAGE(S, BUF) do { \
    const char* _src = (const char*)Wp + (size_t)(S)*32768 + wv*4096 + lane*16; \
    char* _dst = (char*)Sb + 65536 + (size_t)(BUF)*32768 + wv*4096; \
    _Pragma("unroll") \
    for (int i=0;i<4;++i) \
      __builtin_amdgcn_global_load_lds( \
        (const __attribute__((address_space(1))) uint32_t*)(_src + i*1024), \
        (__attribute__((address_space(3))) uint32_t*)(_dst + i*1024), 16, 0, 0); \
  } while(0)

  // prologue: stage step 0 only
  A_STAGE(0, 0); B_STAGE(0, 0);

  for (int t = 0; t < nt; ++t){
    // stage(t) is the only outstanding vmem; it had a full step of cover (t>0)
    asm volatile("s_waitcnt vmcnt(0)" ::: "memory");
    __builtin_amdgcn_s_barrier();          // buf(t&1) staged by all waves; buf(t&1)^1 reads all retired
    __builtin_amdgcn_sched_barrier(0);
    const int cur = t & 1;
    if (t+1 < nt){
      A_STAGE(t+1, cur^1);                 // overlaps the whole compute below
      B_STAGE(t+1, cur^1);
    }

    const u16* Abuf = (const u16*)Sb + (size_t)cur*16384;
    const u16* Bbuf = (const u16*)Sb + 32768 + (size_t)cur*16384;

    f16x8 bh[4], bl[4];
    #pragma unroll
    for (int nf=0;nf<4;++nf){
      bh[nf] = *(const f16x8*)(Bbuf + ((size_t)((wn*4+nf)*2+0)*64 + lane)*8);
      bl[nf] = *(const f16x8*)(Bbuf + ((size_t)((wn*4+nf)*2+1)*64 + lane)*8);
    }
    __builtin_amdgcn_s_setprio(1);
    #pragma unroll
    for (int mf=0;mf<8;++mf){
      const int mfb = wm*8 + mf;
      f16x8 ahf = *(const f16x8*)(Abuf + ((size_t)(mfb*2+0)*64 + lane)*8);
      f16x8 alf = *(const f16x8*)(Abuf + ((size_t)(mfb*2+1)*64 + lane)*8);
      #pragma unroll
      for (int nf=0;nf<4;++nf){
        acc[mf][nf] = __builtin_amdgcn_mfma_f32_16x16x32_f16(ahf, bh[nf], acc[mf][nf], 0,0,0);
        acc[mf][nf] = __builtin_amdgcn_mfma_f32_16x16x32_f16(alf, bh[nf], acc[mf][nf], 0,0,0);
        acc[mf][nf] = __builtin_amdgcn_mfma_f32_16x16x32_f16(ahf, bl[nf], acc[mf][nf], 0,0,0);
      }
    }
    __builtin_amdgcn_s_setprio(0);
  }

  __syncthreads();   // loop LDS dead; safe to overlay

  float bcol[4];
  #pragma unroll
  for (int nf=0;nf<4;++nf) bcol[nf] = bias[wn*64 + nf*16 + (lane&15)];

  if (MODE == 0 || MODE == 1){
    float wyv[4], wxv[4], gy = 0.f;
    if (MODE == 0){
      #pragma unroll
      for (int nf=0;nf<4;++nf){
        int col = wn*64 + nf*16 + (lane&15);
        wyv[nf] = W1[(size_t)3200*HID + col];
        wxv[nf] = W1[(size_t)3201*HID + col];
      }
      gy = -1.f + (2.f/255.f)*(float)y;
    }
    uint32_t* Tr = (uint32_t*)Sb;          // [128][256] packed (hh | ll<<16), 128 KB
    #pragma unroll
    for (int hf=0; hf<2; ++hf){
      if (wm == hf){
        #pragma unroll
        for (int mf=0;mf<8;++mf)
          #pragma unroll
          for (int nf=0;nf<4;++nf)
            #pragma unroll
            for (int j=0;j<4;++j){
              int rl  = mf*16 + (lane>>4)*4 + j;          // 0..127
              int col = wn*64 + nf*16 + (lane&15);
              float z = acc[mf][nf][j] + bcol[nf];
              if (MODE == 0){
                int row = hf*128 + rl;                    // global x in image row
                float gx = -1.f + (2.f/255.f)*(float)row;
                z += gy*wyv[nf] + gx*wxv[nf];
              }
              float h = sinf(30.f*z);
              u16 hh, ll; split2(h, hh, ll);
              Tr[rl*256 + col] = (uint32_t)hh | ((uint32_t)ll << 16);
            }
      }
      __syncthreads();
      // coalesced read-out: 8 units (8 consecutive channels) per thread
      #pragma unroll
      for (int i=0;i<8;++i){
        int u  = i*512 + tid;              // 0..4095
        int r  = u >> 5;                   // 0..127
        int cu = (u & 31) * 8;
        const uint32_t* p = Tr + r*256 + cu;
        uint4 a0 = *(const uint4*)p;
        uint4 a1 = *(const uint4*)(p+4);
        u16x8 vh, vl;
        vh[0]=(u16)a0.x; vl[0]=(u16)(a0.x>>16);
        vh[1]=(u16)a0.y; vl[1]=(u16)(a0.y>>16);
        vh[2]=(u16)a0.z; vl[2]=(u16)(a0.z>>16);
        vh[3]=(u16)a0.w; vl[3]=(u16)(a0.w>>16);
        vh[4]=(u16)a1.x; vl[4]=(u16)(a1.x>>16);
        vh[5]=(u16)a1.y; vl[5]=(u16)(a1.y>>16);
        vh[6]=(u16)a1.z; vl[6]=(u16)(a1.z>>16);
        vh[7]=(u16)a1.w; vl[7]=(u16)(a1.w>>16);
        size_t px = (size_t)(pxb + hf*128 + r);
        *(u16x8*)(Hh + px*HID + cu) = vh;
        *(u16x8*)(Hl + px*HID + cu) = vl;
      }
      __syncthreads();
    }
  } else {
    float (*red)[BPXG][3] = (float(*)[BPXG][3])(void*)Sb;  // 24 KB overlay
    float w4v[4][3];
    #pragma unroll
    for (int nf=0;nf<4;++nf){
      int col = wn*64 + nf*16 + (lane&15);
      w4v[nf][0]=W4[col*3+0]; w4v[nf][1]=W4[col*3+1]; w4v[nf][2]=W4[col*3+2];
    }
    #pragma unroll
    for (int mf=0;mf<8;++mf)
      #pragma unroll
      for (int j=0;j<4;++j){
        float s0=0.f,s1=0.f,s2=0.f;
        #pragma unroll
        for (int nf=0;nf<4;++nf){
          float h = sinf(30.f*(acc[mf][nf][j] + bcol[nf]));
          s0 += h*w4v[nf][0]; s1 += h*w4v[nf][1]; s2 += h*w4v[nf][2];
        }
        #pragma unroll
        for (int m=1;m<16;m<<=1){
          s0 += __shfl_xor(s0, m);
          s1 += __shfl_xor(s1, m);
          s2 += __shfl_xor(s2, m);
        }
        if ((lane & 15) == 0){
          int row = wm*128 + mf*16 + (lane>>4)*4 + j;
          red[wn + wm*4][row][0]=s0; red[wn + wm*4][row][1]=s1; red[wn + wm*4][row][2]=s2;
        }
      }
    __syncthreads();
    for (int o = tid; o < BPXG*3; o += 512){
      int px = o & 255, c = o >> 8;
      int wb = (px >> 7)*4;    // waves with wm = px>>7 hold this row
      float v = red[wb+0][px][c]+red[wb+1][px][c]+red[wb+2][px][c]+red[wb+3][px][c] + b4[c];
      out[(size_t)c*NPX + pxb + px] = v;
    }
  }
#undef A_STAGE
#undef B_STAGE
}

// ---------------------------------------------------------------------------
extern "C" void kernel_launch(void* const* d_in, const int* in_sizes, int n_in,
                              void* d_out, int out_size, void* d_ws, size_t ws_size,
                              hipStream_t stream) {
  const float* xi = (const float*)d_in[0];
  const float* W1 = (const float*)d_in[1];
  const float* b1 = (const float*)d_in[2];
  const float* W2 = (const float*)d_in[3];
  const float* b2 = (const float*)d_in[4];
  const float* W3 = (const float*)d_in[5];
  const float* b3 = (const float*)d_in[6];
  const float* W4 = (const float*)d_in[7];
  const float* b4 = (const float*)d_in[8];
  float* out = (float*)d_out;

  char* ws = (char*)d_ws;
  u16* W1c = (u16*)(ws + OFF_W1C);
  u16* W2p = (u16*)(ws + OFF_W2);
  u16* W3p = (u16*)(ws + OFF_W3);
  u16* Xh  = (u16*)(ws + OFF_XH);
  u16* Xl  = (u16*)(ws + OFF_XL);
  u16* Hh  = (u16*)(ws + OFF_HH);
  u16* Hl  = (u16*)(ws + OFF_HL);

  prep_w1c<<<NS1C*4, 256, 0, stream>>>(W1, W1c);
  prep_w<<<NS2*4, 256, 0, stream>>>(W2, HID, NS2, W2p);
  prep_w<<<NS2*4, 256, 0, stream>>>(W3, HID, NS2, W3p);
  prep_x<<<(NSP + 255)/256, 256, 0, stream>>>(xi, Xh, Xl);

  dim3 grid(NBG), block(512);
  gemm<0><<<grid, block, 0, stream>>>(Xh, Xl, W1c, W1, b1, Hh, Hl,
                                      nullptr, nullptr, nullptr, NS1C);
  gemm<1><<<grid, block, 0, stream>>>(Hh, Hl, W2p, nullptr, b2, Hh, Hl,
                                      nullptr, nullptr, nullptr, NS2);
  gemm<2><<<grid, block, 0, stream>>>(Hh, Hl, W3p, nullptr, b3, nullptr, nullptr,
                                      W4, b4, out, NS2);
}

// Round 16
// 471.126 us; speedup vs baseline: 1.1403x; 1.0760x over previous
//
#include <hip/hip_runtime.h>
#include <math.h>
#include <stdint.h>

typedef _Float16 f16;
typedef _Float16 f16x8 __attribute__((ext_vector_type(8)));
typedef float f32x4 __attribute__((ext_vector_type(4)));
typedef unsigned short u16;
typedef u16 u16x8 __attribute__((ext_vector_type(8)));

#define HID 256
#define NS1C 100              // layer-1 conv K-steps: 25 taps x 4 channel-groups
#define NS2 8                 // 256/32
#define NPX 65536
#define BPXG 256              // pixels per block (one full image row)
#define NBG (NPX/BPXG)        // 256 blocks -> 1 round at 1 block/CU
#define SPAD 260
#define NSP (SPAD*SPAD)

// ws layout (bytes) — same as r13 (~106 MB, fits; proven r9)
#define OFF_W1C 0
#define SZ_W1C  ((size_t)NS1C*32768)
#define OFF_W2  SZ_W1C
#define SZ_W2   ((size_t)NS2*32768)
#define OFF_W3  (OFF_W2+SZ_W2)
#define OFF_XH  ((size_t)4194304)
#define SZ_XP   ((size_t)NSP*128*2)
#define OFF_XL  (OFF_XH + SZ_XP)
#define OFF_HH  (OFF_XL + SZ_XP)
#define SZ_HP   ((size_t)NPX*HID*2)
#define OFF_HL  (OFF_HH + SZ_HP)

__device__ inline void split2(float v, u16& h, u16& l){
  f16 hv = (f16)v;
  f16 lv = (f16)(v - (float)hv);
  h = __builtin_bit_cast(u16, hv);
  l = __builtin_bit_cast(u16, lv);
}

// prep_w: W (fp32 [K][256]) -> fp16 hi/lo MFMA-fragment units (proven layout)
__global__ void prep_w(const float* __restrict__ W, int Kact, int nStages,
                       u16* __restrict__ outp){
  int t = blockIdx.x*256 + threadIdx.x;
  if (t >= nStages*1024) return;
  int s = t >> 10, r = t & 1023;
  int w = r >> 8, nf = (r >> 6) & 3, l = r & 63;
  int col = w*64 + nf*16 + (l & 15);
  int kb  = s*32 + (l >> 4)*8;
  u16x8 hv, lv;
  #pragma unroll
  for (int j = 0; j < 8; ++j){
    int k = kb + j;
    float v = (k < Kact) ? W[(size_t)k*HID + col] : 0.f;
    u16 h, lo; split2(v, h, lo);
    hv[j] = h; lv[j] = lo;
  }
  size_t U0 = ((((size_t)s*4 + w)*4 + nf)*2 + 0)*64 + l;
  *(u16x8*)(outp + U0*8)      = hv;
  *(u16x8*)(outp + (U0+64)*8) = lv;
}

// prep_w1c: W1 rows 0..3199 tap-major (step s: tap=s>>2, cg=s&3; k=c*25+tap)
__global__ void prep_w1c(const float* __restrict__ W1, u16* __restrict__ outp){
  int t = blockIdx.x*256 + threadIdx.x;
  if (t >= NS1C*1024) return;
  int s = t >> 10, r = t & 1023;
  int w = r >> 8, nf = (r >> 6) & 3, l = r & 63;
  int col = w*64 + nf*16 + (l & 15);
  int tap = s >> 2, cg = s & 3;
  int cb  = cg*32 + (l >> 4)*8;
  u16x8 hv, lv;
  #pragma unroll
  for (int j = 0; j < 8; ++j){
    int c = cb + j;
    float v = W1[(size_t)(c*25 + tap)*HID + col];
    u16 h, lo; split2(v, h, lo);
    hv[j] = h; lv[j] = lo;
  }
  size_t U0 = ((((size_t)s*4 + w)*4 + nf)*2 + 0)*64 + l;
  *(u16x8*)(outp + U0*8)      = hv;
  *(u16x8*)(outp + (U0+64)*8) = lv;
}

// prep_x: zero-padded channel-interleaved hi/lo planes (r11-proven)
__global__ __launch_bounds__(256)
void prep_x(const float* __restrict__ xi, u16* __restrict__ Xh, u16* __restrict__ Xl){
  int sp = blockIdx.x*256 + threadIdx.x;
  if (sp >= NSP) return;
  int py = sp / SPAD;
  int px = sp - py*SPAD;
  bool inb = (py >= 2) & (py < 258) & (px >= 2) & (px < 258);
  const float* xin = xi + ((size_t)(py-2)<<8) + (px-2);
  #pragma unroll 4
  for (int cg = 0; cg < 16; ++cg){
    u16x8 hv, lv;
    #pragma unroll
    for (int j = 0; j < 8; ++j){
      float v = inb ? xin[((size_t)(cg*8 + j))<<16] : 0.f;
      u16 h, l; split2(v, h, l); hv[j] = h; lv[j] = l;
    }
    *(u16x8*)(Xh + (size_t)sp*128 + cg*8) = hv;
    *(u16x8*)(Xl + (size_t)sp*128 + cg*8) = lv;
  }
}

// ---------------------------------------------------------------------------
// 256px x 256col GEMM, 512 thr = 8 waves (wave = 128px x 64col, 96 MFMA/step).
// One barrier/step, counted-vmcnt discipline (r15-proven), TERM-MAJOR MFMA
// ordering: per half (4 mfb), 3 passes of 16 INDEPENDENT MFMAs (hh, lh, hl).
// Per-acc term order unchanged (hh->lh->hl) => bitwise-identical results;
// dependency distance 16 MFMAs removes in-order issue stalls on acc chains.
// MODE 0: A = conv taps of Xh/Xl, nt=100, exact-f32 coords in epilogue.
// MODE 1: A = Hh/Hl, nt=8. MODE 2: + fused layer-4 tail.
// ---------------------------------------------------------------------------
template<int MODE>
__global__ __launch_bounds__(512, 2)
void gemm(const u16* __restrict__ Ah, const u16* __restrict__ Al,
          const u16* __restrict__ Wp, const float* __restrict__ W1,
          const float* __restrict__ bias, u16* __restrict__ Hh, u16* __restrict__ Hl,
          const float* __restrict__ W4, const float* __restrict__ b4,
          float* __restrict__ out, int nt)
{
  __shared__ __align__(16) u16 Sb[65536];   // 128 KB pool: A@{0,32K}, B@{64K,96K}

  const int tid  = threadIdx.x;
  const int lane = tid & 63;
  const int wv   = tid >> 6;            // 0..7
  const int wm   = wv >> 2, wn = wv & 3;

  int bid = blockIdx.x;
  bid = (bid & 7)*(NBG/8) + (bid >> 3);   // XCD-chunked swizzle (256%8==0)
  const int pxb = bid * BPXG;             // one full image row
  const int y   = bid;                    // row index

  f32x4 acc[8][4];
  #pragma unroll
  for (int a=0;a<8;a++)
    #pragma unroll
    for (int bq=0;bq<4;bq++) acc[a][bq] = f32x4{0.f,0.f,0.f,0.f};

  // A-stage: wave wv stages mfb = wv*2+u (u=0,1), hi+lo -> 4 DMA/thread.
#define A_STAGE(S, BUF) do { \
    _Pragma("unroll") \
    for (int u=0;u<2;++u){ \
      const int mfb = wv*2 + u; \
      size_t off; \
      if (MODE == 0){ \
        const int tap = (S) >> 2, cg = (S) & 3; \
        const int dy = tap/5, dx = tap - 5*dy; \
        const int sp = (y + dy)*SPAD + dx + mfb*16 + (lane & 15); \
        off = (size_t)sp*128 + cg*32 + (lane >> 4)*8; \
      } else { \
        const int px = pxb + mfb*16 + (lane & 15); \
        off = (size_t)px*HID + (S)*32 + (lane >> 4)*8; \
      } \
      __builtin_amdgcn_global_load_lds( \
        (const __attribute__((address_space(1))) uint32_t*)(Ah + off), \
        (__attribute__((address_space(3))) uint32_t*)((char*)Sb + (size_t)(BUF)*32768 + (mfb*2+0)*1024), \
        16, 0, 0); \
      __builtin_amdgcn_global_load_lds( \
        (const __attribute__((address_space(1))) uint32_t*)(Al + off), \
        (__attribute__((address_space(3))) uint32_t*)((char*)Sb + (size_t)(BUF)*32768 + (mfb*2+1)*1024), \
        16, 0, 0); \
    } \
  } while(0)

  // B-stage: linear 32 KB slab copy; wave wv covers [wv*4096, +4096) -> 4 DMA/thread.
#define B_STAGE(S, BUF) do { \
    const char* _src = (const char*)Wp + (size_t)(S)*32768 + wv*4096 + lane*16; \
    char* _dst = (char*)Sb + 65536 + (size_t)(BUF)*32768 + wv*4096; \
    _Pragma("unroll") \
    for (int i=0;i<4;++i) \
      __builtin_amdgcn_global_load_lds( \
        (const __attribute__((address_space(1))) uint32_t*)(_src + i*1024), \
        (__attribute__((address_space(3))) uint32_t*)(_dst + i*1024), 16, 0, 0); \
  } while(0)

  // prologue: stage step 0 only
  A_STAGE(0, 0); B_STAGE(0, 0);

  for (int t = 0; t < nt; ++t){
    // stage(t) is the only outstanding vmem; it had a full step of cover (t>0)
    asm volatile("s_waitcnt vmcnt(0)" ::: "memory");
    __builtin_amdgcn_s_barrier();          // buf(t&1) staged; other buf's reads all retired
    __builtin_amdgcn_sched_barrier(0);
    const int cur = t & 1;
    if (t+1 < nt){
      A_STAGE(t+1, cur^1);                 // overlaps the whole compute below
      B_STAGE(t+1, cur^1);
    }

    const u16* Abuf = (const u16*)Sb + (size_t)cur*16384;
    const u16* Bbuf = (const u16*)Sb + 32768 + (size_t)cur*16384;

    f16x8 bh[4], bl[4];
    #pragma unroll
    for (int nf=0;nf<4;++nf){
      bh[nf] = *(const f16x8*)(Bbuf + ((size_t)((wn*4+nf)*2+0)*64 + lane)*8);
      bl[nf] = *(const f16x8*)(Bbuf + ((size_t)((wn*4+nf)*2+1)*64 + lane)*8);
    }
    __builtin_amdgcn_s_setprio(1);
    #pragma unroll
    for (int hf=0; hf<2; ++hf){
      f16x8 ahv[4], alv[4];
      #pragma unroll
      for (int m=0;m<4;++m){
        const int mfb = wm*8 + hf*4 + m;
        ahv[m] = *(const f16x8*)(Abuf + ((size_t)(mfb*2+0)*64 + lane)*8);
        alv[m] = *(const f16x8*)(Abuf + ((size_t)(mfb*2+1)*64 + lane)*8);
      }
      // pass 1: Ah*Bh — 16 independent MFMAs
      #pragma unroll
      for (int m=0;m<4;++m)
        #pragma unroll
        for (int nf=0;nf<4;++nf)
          acc[hf*4+m][nf] = __builtin_amdgcn_mfma_f32_16x16x32_f16(ahv[m], bh[nf], acc[hf*4+m][nf], 0,0,0);
      // pass 2: Al*Bh — 16 independent MFMAs
      #pragma unroll
      for (int m=0;m<4;++m)
        #pragma unroll
        for (int nf=0;nf<4;++nf)
          acc[hf*4+m][nf] = __builtin_amdgcn_mfma_f32_16x16x32_f16(alv[m], bh[nf], acc[hf*4+m][nf], 0,0,0);
      // pass 3: Ah*Bl — 16 independent MFMAs
      #pragma unroll
      for (int m=0;m<4;++m)
        #pragma unroll
        for (int nf=0;nf<4;++nf)
          acc[hf*4+m][nf] = __builtin_amdgcn_mfma_f32_16x16x32_f16(ahv[m], bl[nf], acc[hf*4+m][nf], 0,0,0);
    }
    __builtin_amdgcn_s_setprio(0);
  }

  __syncthreads();   // loop LDS dead; MODE 2 overlays Sb

  float bcol[4];
  #pragma unroll
  for (int nf=0;nf<4;++nf) bcol[nf] = bias[wn*64 + nf*16 + (lane&15)];

  if (MODE == 0){
    float wyv[4], wxv[4];
    #pragma unroll
    for (int nf=0;nf<4;++nf){
      int col = wn*64 + nf*16 + (lane&15);
      wyv[nf] = W1[(size_t)3200*HID + col];
      wxv[nf] = W1[(size_t)3201*HID + col];
    }
    const float gy = -1.f + (2.f/255.f)*(float)y;
    #pragma unroll
    for (int mf=0;mf<8;++mf)
      #pragma unroll
      for (int nf=0;nf<4;++nf)
        #pragma unroll
        for (int j=0;j<4;++j){
          int row = wm*128 + mf*16 + (lane>>4)*4 + j;          // 0..255 = x coord
          float gx = -1.f + (2.f/255.f)*(float)row;
          float z = acc[mf][nf][j] + bcol[nf] + gy*wyv[nf] + gx*wxv[nf];
          float h = sinf(30.f*z);
          u16 hh,ll; split2(h,hh,ll);
          int col = wn*64 + nf*16 + (lane&15);
          size_t o = (size_t)(pxb+row)*HID + col;
          Hh[o] = hh; Hl[o] = ll;
        }
  } else if (MODE == 1){
    #pragma unroll
    for (int mf=0;mf<8;++mf)
      #pragma unroll
      for (int nf=0;nf<4;++nf)
        #pragma unroll
        for (int j=0;j<4;++j){
          float z = acc[mf][nf][j] + bcol[nf];
          float h = sinf(30.f*z);
          u16 hh,ll; split2(h,hh,ll);
          int row = wm*128 + mf*16 + (lane>>4)*4 + j;
          int col = wn*64 + nf*16 + (lane&15);
          size_t o = (size_t)(pxb+row)*HID + col;
          Hh[o] = hh; Hl[o] = ll;
        }
  } else {
    float (*red)[BPXG][3] = (float(*)[BPXG][3])(void*)Sb;  // 24 KB overlay, bufs dead
    float w4v[4][3];
    #pragma unroll
    for (int nf=0;nf<4;++nf){
      int col = wn*64 + nf*16 + (lane&15);
      w4v[nf][0]=W4[col*3+0]; w4v[nf][1]=W4[col*3+1]; w4v[nf][2]=W4[col*3+2];
    }
    #pragma unroll
    for (int mf=0;mf<8;++mf)
      #pragma unroll
      for (int j=0;j<4;++j){
        float s0=0.f,s1=0.f,s2=0.f;
        #pragma unroll
        for (int nf=0;nf<4;++nf){
          float h = sinf(30.f*(acc[mf][nf][j] + bcol[nf]));
          s0 += h*w4v[nf][0]; s1 += h*w4v[nf][1]; s2 += h*w4v[nf][2];
        }
        #pragma unroll
        for (int m=1;m<16;m<<=1){
          s0 += __shfl_xor(s0, m);
          s1 += __shfl_xor(s1, m);
          s2 += __shfl_xor(s2, m);
        }
        if ((lane & 15) == 0){
          int row = wm*128 + mf*16 + (lane>>4)*4 + j;
          red[wn + wm*4][row][0]=s0; red[wn + wm*4][row][1]=s1; red[wn + wm*4][row][2]=s2;
        }
      }
    __syncthreads();
    for (int o = tid; o < BPXG*3; o += 512){
      int px = o & 255, c = o >> 8;
      int wb = (px >> 7)*4;    // waves with wm = px>>7 hold this row
      float v = red[wb+0][px][c]+red[wb+1][px][c]+red[wb+2][px][c]+red[wb+3][px][c] + b4[c];
      out[(size_t)c*NPX + pxb + px] = v;
    }
  }
#undef A_STAGE
#undef B_STAGE
}

// ---------------------------------------------------------------------------
extern "C" void kernel_launch(void* const* d_in, const int* in_sizes, int n_in,
                              void* d_out, int out_size, void* d_ws, size_t ws_size,
                              hipStream_t stream) {
  const float* xi = (const float*)d_in[0];
  const float* W1 = (const float*)d_in[1];
  const float* b1 = (const float*)d_in[2];
  const float* W2 = (const float*)d_in[3];
  const float* b2 = (const float*)d_in[4];
  const float* W3 = (const float*)d_in[5];
  const float* b3 = (const float*)d_in[6];
  const float* W4 = (const float*)d_in[7];
  const float* b4 = (const float*)d_in[8];
  float* out = (float*)d_out;

  char* ws = (char*)d_ws;
  u16* W1c = (u16*)(ws + OFF_W1C);
  u16* W2p = (u16*)(ws + OFF_W2);
  u16* W3p = (u16*)(ws + OFF_W3);
  u16* Xh  = (u16*)(ws + OFF_XH);
  u16* Xl  = (u16*)(ws + OFF_XL);
  u16* Hh  = (u16*)(ws + OFF_HH);
  u16* Hl  = (u16*)(ws + OFF_HL);

  prep_w1c<<<NS1C*4, 256, 0, stream>>>(W1, W1c);
  prep_w<<<NS2*4, 256, 0, stream>>>(W2, HID, NS2, W2p);
  prep_w<<<NS2*4, 256, 0, stream>>>(W3, HID, NS2, W3p);
  prep_x<<<(NSP + 255)/256, 256, 0, stream>>>(xi, Xh, Xl);

  dim3 grid(NBG), block(512);
  gemm<0><<<grid, block, 0, stream>>>(Xh, Xl, W1c, W1, b1, Hh, Hl,
                                      nullptr, nullptr, nullptr, NS1C);
  gemm<1><<<grid, block, 0, stream>>>(Hh, Hl, W2p, nullptr, b2, Hh, Hl,
                                      nullptr, nullptr, nullptr, NS2);
  gemm<2><<<grid, block, 0, stream>>>(Hh, Hl, W3p, nullptr, b3, nullptr, nullptr,
                                      W4, b4, out, NS2);
}